// Round 13
// baseline (41.198 us; speedup 1.0000x reference)
//
#include <hip/hip_runtime.h>

#define HRR 256
#define LSZ 64
#define KK  15
#define PROWS 267
#define PCOLS 272

typedef _Float16 half8  __attribute__((ext_vector_type(8)));
typedef __fp16   fp16x2 __attribute__((ext_vector_type(2)));
typedef __fp16   h2     __attribute__((ext_vector_type(2)));
typedef float    f32x16 __attribute__((ext_vector_type(16)));

#define PACK_THREADS 17152   // 67 blocks
#define PAD_N (32 * PROWS * PCOLS)

// ---------------------------------------------------------------------------
// Prep kernel: weight packing (blocks 0..66) + hrhs zero-padding (rest).
// Unchanged (verified rounds 6-12).
// ---------------------------------------------------------------------------
__global__ __launch_bounds__(256) void prep_kernel(
    const float* __restrict__ w1,     const float* __restrict__ b1,
    const float* __restrict__ w2,     const float* __restrict__ b2,
    const float* __restrict__ w_spek, const float* __restrict__ b_spek,
    const float* __restrict__ w_spak, const float* __restrict__ b_spak,
    const float* __restrict__ hrhs,
    _Float16* __restrict__ w2p, _Float16* __restrict__ whp,
    _Float16* __restrict__ w1p, float* __restrict__ pad)
{
    int gid = blockIdx.x * 256 + threadIdx.x;
    if (gid < PACK_THREADS) {
        int flat = gid;
        if (flat < 14336) {
            int rt = flat / 7168;
            int rem = flat % 7168;
            int f  = rem / 512;
            int r2 = rem % 512;
            int ln = r2 / 8;
            int i  = r2 % 8;
            int j = rt * 32 + (ln & 31);
            int k = f * 16 + (ln >> 5) * 8 + i;
            float v = 0.0f;
            if (j < 50) {
                if (k < 200)       v = w2[k * 50 + j];
                else if (k == 200) v = b2[j];
            }
            w2p[flat] = (_Float16)v;
        } else if (flat < 14336 + 2048) {
            int r  = flat - 14336;
            int f  = r / 512;
            int r2 = r % 512;
            int ln = r2 / 8;
            int i  = r2 % 8;
            int t = ln & 31;
            int k = f * 16 + (ln >> 5) * 8 + i;
            float v = 0.0f;
            if (t < 9) {
                if (k < 50)       v = (t < 5) ? w_spek[k * 5 + t] : w_spak[k * 4 + (t - 5)];
                else if (k == 50) v = (t < 5) ? b_spek[t] : b_spak[t - 5];
            }
            whp[r] = (_Float16)v;
        } else if (flat < 14336 + 2048 + 624) {
            int r = flat - (14336 + 2048);
            int e  = r & 1;
            int pr = (r >> 1) % 12;
            int hl = ((r >> 1) / 12) & 1;
            int f  = (r >> 1) / 24;
            int k  = f * 16 + hl * 8 + (pr & 3) * 2 + e;
            int sel = pr >> 2;                  // 0 wa, 1 wb, 2 bv
            float v = 0.0f;
            if (k < 200)       v = (sel == 0) ? w1[k] : (sel == 1) ? w1[200 + k] : b1[k];
            else if (k == 200 && sel == 2) v = 1.0f;   // bias ones-row
            w1p[r] = (_Float16)v;
        }
    } else {
        int i = gid - PACK_THREADS;
        if (i < PAD_N) {
            int pc   = i % PCOLS;
            int rest = i / PCOLS;
            int pr   = rest % PROWS;
            int bc   = rest / PROWS;
            int r    = pr - 6;
            int col  = pc - 6;
            float v = ((unsigned)r < 256u && (unsigned)col < 256u)
                          ? hrhs[(bc << 16) + (r << 8) + col] : 0.0f;
            pad[i] = v;
        }
    }
}

// ---------------------------------------------------------------------------
// Main MLP kernel, round-13: 32 points per wave (was 64). Halves the AGPR
// accumulator footprint (96 -> 48 regs/lane) against the UNIFIED gfx950
// VGPR/AGPR pool -> real occupancy ~3 -> ~5 waves/SIMD. Per-point MFMA and
// VALU unchanged; lanes cl / cl+32 both serve point cl (stores gated hl==0).
// All fragment/shuffle mappings are the verified round-8 ones, ct removed.
// ---------------------------------------------------------------------------
__global__ __launch_bounds__(512, 4) void mlp10_kernel(
    const float* __restrict__ coords, const float* __restrict__ hrhs,
    const _Float16* __restrict__ w1p,
    const _Float16* __restrict__ w2p, const _Float16* __restrict__ whp,
    float* __restrict__ out_pan,      float* __restrict__ inv_ws)
{
    __shared__ __align__(16) _Float16 W2s[14336];   // 28672 B
    __shared__ __align__(16) _Float16 W1s[624];     // 1248 B

    const int tid  = threadIdx.x;
    const int lane = tid & 63;
    const int wv   = tid >> 6;      // 0..7
    const int hl   = lane >> 5;
    const int cl   = lane & 31;

    {
        const uint4* src = (const uint4*)w2p;
        uint4* dst = (uint4*)W2s;
        #pragma unroll
        for (int it = 0; it < 3; ++it)
            dst[it * 512 + tid] = src[it * 512 + tid];
        if (tid < 256) dst[1536 + tid] = src[1536 + tid];
        if (tid < 312) ((unsigned*)W1s)[tid] = ((const unsigned*)w1p)[tid];
    }
    __syncthreads();

    // 8 waves x 32 points = 256 points per block
    const int p0w = blockIdx.x * 256 + wv * 32;

    const float2 cA = ((const float2*)coords)[p0w + cl];

    const __fp16 ax = (__fp16)cA.x, ay = (__fp16)cA.y;
    const h2 cax2 = {ax, ax}, cay2 = {ay, ay};
    const h2 hz   = {(__fp16)0.f, (__fp16)0.f};

    f32x16 acc00, acc10;
    #pragma unroll
    for (int r = 0; r < 16; ++r) { acc00[r] = 0.f; acc10[r] = 0.f; }

    const _Float16* w1base = W1s + hl * 24;

    for (int f = 0; f < 13; ++f) {
        half8 a0 = *(const half8*)(W2s + f * 512 + lane * 8);
        half8 a1 = *(const half8*)(W2s + (14 + f) * 512 + lane * 8);

        union { uint4 u[3]; h2 p[12]; } W;
        const uint4* wp = (const uint4*)(w1base + f * 48);
        W.u[0] = wp[0]; W.u[1] = wp[1]; W.u[2] = wp[2];

        union { half8 h; h2 p[4]; } B0;
        #pragma unroll
        for (int m = 0; m < 4; ++m) {
            h2 t0 = __builtin_elementwise_fma(W.p[4 + m], cay2, W.p[8 + m]);
            h2 r0 = __builtin_elementwise_fma(W.p[m],     cax2, t0);
            B0.p[m] = __builtin_elementwise_max(r0, hz);
        }

        acc00 = __builtin_amdgcn_mfma_f32_32x32x16_f16(a0, B0.h, acc00, 0, 0, 0);
        acc10 = __builtin_amdgcn_mfma_f32_32x32x16_f16(a1, B0.h, acc10, 0, 0, 0);
    }

    // pk0 = F rows 0..31, pk1 = rows 32..63 (col = point cl)
    uint32_t pk0[8], pk1[8];
    #pragma unroll
    for (int m = 0; m < 8; ++m) {
        union { fp16x2 p; uint32_t u; } q;
        q.p = __builtin_amdgcn_cvt_pkrtz(fmaxf(acc00[2*m], 0.f), fmaxf(acc00[2*m+1], 0.f));
        pk0[m] = q.u;
        q.p = __builtin_amdgcn_cvt_pkrtz(fmaxf(acc10[2*m], 0.f), fmaxf(acc10[2*m+1], 0.f));
        pk1[m] = q.u;
    }
    if (hl == 0) pk1[5] = 0x3C00u;   // F-row 50 = 1 (head-bias row)

    f32x16 acch;
    #pragma unroll
    for (int r = 0; r < 16; ++r) acch[r] = 0.f;

    #pragma unroll
    for (int kt = 0; kt < 4; ++kt) {
        half8 ah = *(const half8*)(whp + kt * 512 + lane * 8);
        const int bb = 4 * (kt & 1);
        const uint32_t e0 = (kt < 2) ? pk0[bb + 0] : pk1[bb + 0];
        const uint32_t e1 = (kt < 2) ? pk0[bb + 1] : pk1[bb + 1];
        const uint32_t e2 = (kt < 2) ? pk0[bb + 2] : pk1[bb + 2];
        const uint32_t e3 = (kt < 2) ? pk0[bb + 3] : pk1[bb + 3];
        const uint32_t o0 = hl ? e2 : e0;
        const uint32_t o1 = hl ? e3 : e1;
        const uint32_t s0 = hl ? e0 : e2;
        const uint32_t s1 = hl ? e1 : e3;
        const uint32_t g0 = (uint32_t)__shfl_xor((int)s0, 32);
        const uint32_t g1 = (uint32_t)__shfl_xor((int)s1, 32);
        union { half8 h; uint32_t u[4]; } BF;
        BF.u[0] = hl ? g0 : o0;
        BF.u[1] = hl ? g1 : o1;
        BF.u[2] = hl ? o0 : g0;
        BF.u[3] = hl ? o1 : g1;
        acch = __builtin_amdgcn_mfma_f32_32x32x16_f16(ah, BF.h, acch, 0, 0, 0);
    }

    // gather heads for point cl: hl0 holds t0-3 (r0-3) + t8 (r4); hl1 t4-7.
    float s[9];
    #pragma unroll
    for (int r = 0; r < 4; ++r) {
        const float own = acch[r];
        const float got = __shfl_xor(own, 32);
        s[r]     = hl ? got : own;
        s[4 + r] = hl ? own : got;
    }
    {
        const float own = acch[4];
        const float got = __shfl_xor(own, 32);
        s[8] = hl ? got : own;
    }

    const int p   = p0w + cl;
    const int b   = p >> 16;
    const int pix = p & 65535;
    const int ph  = pix >> 8;
    const int pw  = pix & 255;

    float pan = s[4];
    #pragma unroll
    for (int c = 0; c < 4; ++c)
        pan = fmaf(hrhs[((b * 4 + c) << 16) + pix], s[c], pan);

    if (hl == 0) {
        out_pan[p] = pan;
        if ((ph & 3) == 1 && (pw & 3) == 1) {
            const float v0 = s[5], v2 = s[7], v3 = s[8];
            const int hh = ph >> 2, ww = pw >> 2;
            const int o = ((b * LSZ + hh) * LSZ + ww) * 3;
            inv_ws[o + 0] = v0 * v0 + v2 * v2;
            inv_ws[o + 1] = v2 * v3;
            inv_ws[o + 2] = v3 * v3;
        }
    }
}

// ---------------------------------------------------------------------------
// msi2 (unchanged, verified): shared Gaussian weights in LDS + float4
// gathers from padded planes.
// ---------------------------------------------------------------------------
__global__ __launch_bounds__(256) void msi2_kernel(
    const float* __restrict__ pad, const float* __restrict__ inv_ws,
    float* __restrict__ out_msi)
{
    __shared__ float ew[225 * 64];   // 57600 B, [p*15+q][ww]
    __shared__ float wsp[256];

    const int tid = threadIdx.x;
    const int ww  = tid & 63;
    const int c   = tid >> 6;
    const int hh  = blockIdx.x & 63;
    const int b   = blockIdx.x >> 6;

    const int o = ((b * LSZ + hh) * LSZ + ww) * 3;
    const float I00 = inv_ws[o + 0];
    const float I01 = inv_ws[o + 1];
    const float I11 = inv_ws[o + 2];

    float ws = 0.0f;
    #pragma unroll
    for (int pp = 0; pp < 4; ++pp) {
        const int p = c * 4 + pp;
        if (p > 14) break;
        const float dp = (float)(p - 7);
        const float a0 = I00 * dp * dp;
        const float a1 = 2.0f * I01 * dp;
        #pragma unroll
        for (int q = 0; q < 15; ++q) {
            const float dq = (float)(q - 7);
            const float tt = fmaf(a1, dq, fmaf(I11 * dq, dq, a0));
            const float e = __expf(-0.5f * tt);
            ew[(p * 15 + q) * 64 + ww] = e;
            ws += e;
        }
    }
    wsp[tid] = ws;
    __syncthreads();

    const float wsum = wsp[ww] + wsp[64 + ww] + wsp[128 + ww] + wsp[192 + ww];
    const float* plane = pad + (size_t)((b * 4 + c) * PROWS) * PCOLS;

    float acc = 0.0f;
    #pragma unroll
    for (int p = 0; p < 15; ++p) {
        const float* rowp = plane + (4 * hh + p) * PCOLS + 4 * ww;
        const float4 x0 = *(const float4*)(rowp);
        const float4 x1 = *(const float4*)(rowp + 4);
        const float4 x2 = *(const float4*)(rowp + 8);
        const float4 x3 = *(const float4*)(rowp + 12);
        const float xs[16] = {x0.x,x0.y,x0.z,x0.w, x1.x,x1.y,x1.z,x1.w,
                              x2.x,x2.y,x2.z,x2.w, x3.x,x3.y,x3.z,x3.w};
        #pragma unroll
        for (int q = 0; q < 15; ++q)
            acc = fmaf(xs[q], ew[(p * 15 + q) * 64 + ww], acc);
    }
    out_msi[((b * 4 + c) * LSZ + hh) * LSZ + ww] = acc / wsum;
}

extern "C" void kernel_launch(void* const* d_in, const int* in_sizes, int n_in,
                              void* d_out, int out_size, void* d_ws, size_t ws_size,
                              hipStream_t stream) {
    const float* coords = (const float*)d_in[0];
    const float* hrhs   = (const float*)d_in[1];
    const float* w1     = (const float*)d_in[2];
    const float* b1     = (const float*)d_in[3];
    const float* w2     = (const float*)d_in[4];
    const float* b2     = (const float*)d_in[5];
    const float* w_spek = (const float*)d_in[6];
    const float* b_spek = (const float*)d_in[7];
    const float* w_spak = (const float*)d_in[8];
    const float* b_spak = (const float*)d_in[9];

    float* out     = (float*)d_out;
    float* out_msi = out;                        // 8*4*64*64   = 131072
    float* out_pan = out + 8 * 4 * 64 * 64;      // 8*1*256*256 = 524288

    float*     inv_ws = (float*)d_ws;                         // 393216 B
    _Float16*  w2p    = (_Float16*)((char*)d_ws + 393216);    // 28672 B
    _Float16*  whp    = (_Float16*)((char*)d_ws + 421888);    // 4096 B
    _Float16*  w1p    = (_Float16*)((char*)d_ws + 425984);    // 4096 B (1248 used)
    float*     padbuf = (float*)((char*)d_ws + 430080);       // 9295872 B

    const int n_prep = PACK_THREADS / 256 + PAD_N / 256;      // 67 + 9078
    prep_kernel<<<n_prep, 256, 0, stream>>>(
        w1, b1, w2, b2, w_spek, b_spek, w_spak, b_spak, hrhs,
        w2p, whp, w1p, padbuf);

    mlp10_kernel<<<2048, 512, 0, stream>>>(
        coords, hrhs, w1p, w2p, whp, out_pan, inv_ws);

    msi2_kernel<<<512, 256, 0, stream>>>(padbuf, inv_ws, out_msi);
}

// Round 14
// 39.267 us; speedup vs baseline: 1.0492x; 1.0492x over previous
//
#include <hip/hip_runtime.h>

#define HRR 256
#define LSZ 64
#define KK  15
#define PROWS 267
#define PCOLS 272

typedef _Float16 half8  __attribute__((ext_vector_type(8)));
typedef __fp16   fp16x2 __attribute__((ext_vector_type(2)));
typedef __fp16   h2     __attribute__((ext_vector_type(2)));
typedef float    f32x16 __attribute__((ext_vector_type(16)));

#define PACK_THREADS 17152   // 67 blocks
#define PAD_N (32 * PROWS * PCOLS)

// ---------------------------------------------------------------------------
// Prep kernel: weight packing (blocks 0..66) + hrhs zero-padding (rest).
// Unchanged (verified rounds 6-13).
// ---------------------------------------------------------------------------
__global__ __launch_bounds__(256) void prep_kernel(
    const float* __restrict__ w1,     const float* __restrict__ b1,
    const float* __restrict__ w2,     const float* __restrict__ b2,
    const float* __restrict__ w_spek, const float* __restrict__ b_spek,
    const float* __restrict__ w_spak, const float* __restrict__ b_spak,
    const float* __restrict__ hrhs,
    _Float16* __restrict__ w2p, _Float16* __restrict__ whp,
    _Float16* __restrict__ w1p, float* __restrict__ pad)
{
    int gid = blockIdx.x * 256 + threadIdx.x;
    if (gid < PACK_THREADS) {
        int flat = gid;
        if (flat < 14336) {
            int rt = flat / 7168;
            int rem = flat % 7168;
            int f  = rem / 512;
            int r2 = rem % 512;
            int ln = r2 / 8;
            int i  = r2 % 8;
            int j = rt * 32 + (ln & 31);
            int k = f * 16 + (ln >> 5) * 8 + i;
            float v = 0.0f;
            if (j < 50) {
                if (k < 200)       v = w2[k * 50 + j];
                else if (k == 200) v = b2[j];
            }
            w2p[flat] = (_Float16)v;
        } else if (flat < 14336 + 2048) {
            int r  = flat - 14336;
            int f  = r / 512;
            int r2 = r % 512;
            int ln = r2 / 8;
            int i  = r2 % 8;
            int t = ln & 31;
            int k = f * 16 + (ln >> 5) * 8 + i;
            float v = 0.0f;
            if (t < 9) {
                if (k < 50)       v = (t < 5) ? w_spek[k * 5 + t] : w_spak[k * 4 + (t - 5)];
                else if (k == 50) v = (t < 5) ? b_spek[t] : b_spak[t - 5];
            }
            whp[r] = (_Float16)v;
        } else if (flat < 14336 + 2048 + 624) {
            int r = flat - (14336 + 2048);
            int e  = r & 1;
            int pr = (r >> 1) % 12;
            int hl = ((r >> 1) / 12) & 1;
            int f  = (r >> 1) / 24;
            int k  = f * 16 + hl * 8 + (pr & 3) * 2 + e;
            int sel = pr >> 2;                  // 0 wa, 1 wb, 2 bv
            float v = 0.0f;
            if (k < 200)       v = (sel == 0) ? w1[k] : (sel == 1) ? w1[200 + k] : b1[k];
            else if (k == 200 && sel == 2) v = 1.0f;   // bias ones-row
            w1p[r] = (_Float16)v;
        }
    } else {
        int i = gid - PACK_THREADS;
        if (i < PAD_N) {
            int pc   = i % PCOLS;
            int rest = i / PCOLS;
            int pr   = rest % PROWS;
            int bc   = rest / PROWS;
            int r    = pr - 6;
            int col  = pc - 6;
            float v = ((unsigned)r < 256u && (unsigned)col < 256u)
                          ? hrhs[(bc << 16) + (r << 8) + col] : 0.0f;
            pad[i] = v;
        }
    }
}

// ---------------------------------------------------------------------------
// Main MLP kernel, round-14: round-12 winner (512-thread blocks, 64 pts/wave)
// with ONE change: #pragma unroll on the 13-step f-loop. Rolled, the loop
// forced per-iteration ds_read -> lgkmcnt -> VALU -> MFMA round trips
// (~120 cyc LDS latency exposed 13x; VGPR=52 proves no pipelining).
// Unrolled, all ds_read addresses become base+imm and the scheduler can
// issue loads 2-3 iterations ahead under MFMA/VALU.
// ---------------------------------------------------------------------------
__global__ __launch_bounds__(512, 4) void mlp11_kernel(
    const float* __restrict__ coords, const float* __restrict__ hrhs,
    const _Float16* __restrict__ w1p,
    const _Float16* __restrict__ w2p, const _Float16* __restrict__ whp,
    float* __restrict__ out_pan,      float* __restrict__ inv_ws)
{
    __shared__ __align__(16) _Float16 W2s[14336];   // 28672 B
    __shared__ __align__(16) _Float16 W1s[624];     // 1248 B

    const int tid  = threadIdx.x;
    const int lane = tid & 63;
    const int wv   = tid >> 6;      // 0..7
    const int hl   = lane >> 5;
    const int cl   = lane & 31;

    {
        const uint4* src = (const uint4*)w2p;
        uint4* dst = (uint4*)W2s;
        #pragma unroll
        for (int it = 0; it < 3; ++it)
            dst[it * 512 + tid] = src[it * 512 + tid];
        if (tid < 256) dst[1536 + tid] = src[1536 + tid];
        if (tid < 312) ((unsigned*)W1s)[tid] = ((const unsigned*)w1p)[tid];
    }
    __syncthreads();

    const int p0 = blockIdx.x * 512 + wv * 64;

    const float2 cA = ((const float2*)coords)[p0 + cl];        // ct = 0
    const float2 cB = ((const float2*)coords)[p0 + 32 + cl];   // ct = 1

    const __fp16 ax = (__fp16)cA.x, ay = (__fp16)cA.y;
    const __fp16 bx = (__fp16)cB.x, by = (__fp16)cB.y;
    const h2 cax2 = {ax, ax}, cay2 = {ay, ay};
    const h2 cbx2 = {bx, bx}, cby2 = {by, by};
    const h2 hz   = {(__fp16)0.f, (__fp16)0.f};

    f32x16 acc00, acc01, acc10, acc11;
    #pragma unroll
    for (int r = 0; r < 16; ++r) { acc00[r] = 0.f; acc01[r] = 0.f; acc10[r] = 0.f; acc11[r] = 0.f; }

    const _Float16* w1base = W1s + hl * 24;

    #pragma unroll
    for (int f = 0; f < 13; ++f) {
        half8 a0 = *(const half8*)(W2s + f * 512 + lane * 8);
        half8 a1 = *(const half8*)(W2s + (14 + f) * 512 + lane * 8);

        union { uint4 u[3]; h2 p[12]; } W;
        const uint4* wp = (const uint4*)(w1base + f * 48);
        W.u[0] = wp[0]; W.u[1] = wp[1]; W.u[2] = wp[2];

        union { half8 h; h2 p[4]; } B0, B1;
        #pragma unroll
        for (int m = 0; m < 4; ++m) {
            h2 t0 = __builtin_elementwise_fma(W.p[4 + m], cay2, W.p[8 + m]);
            h2 r0 = __builtin_elementwise_fma(W.p[m],     cax2, t0);
            B0.p[m] = __builtin_elementwise_max(r0, hz);
            h2 t1 = __builtin_elementwise_fma(W.p[4 + m], cby2, W.p[8 + m]);
            h2 r1 = __builtin_elementwise_fma(W.p[m],     cbx2, t1);
            B1.p[m] = __builtin_elementwise_max(r1, hz);
        }

        acc00 = __builtin_amdgcn_mfma_f32_32x32x16_f16(a0, B0.h, acc00, 0, 0, 0);
        acc01 = __builtin_amdgcn_mfma_f32_32x32x16_f16(a0, B1.h, acc01, 0, 0, 0);
        acc10 = __builtin_amdgcn_mfma_f32_32x32x16_f16(a1, B0.h, acc10, 0, 0, 0);
        acc11 = __builtin_amdgcn_mfma_f32_32x32x16_f16(a1, B1.h, acc11, 0, 0, 0);
    }

    uint32_t pk0[2][8], pk1[2][8];
    #pragma unroll
    for (int m = 0; m < 8; ++m) {
        union { fp16x2 p; uint32_t u; } q;
        q.p = __builtin_amdgcn_cvt_pkrtz(fmaxf(acc00[2*m], 0.f), fmaxf(acc00[2*m+1], 0.f));
        pk0[0][m] = q.u;
        q.p = __builtin_amdgcn_cvt_pkrtz(fmaxf(acc01[2*m], 0.f), fmaxf(acc01[2*m+1], 0.f));
        pk0[1][m] = q.u;
        q.p = __builtin_amdgcn_cvt_pkrtz(fmaxf(acc10[2*m], 0.f), fmaxf(acc10[2*m+1], 0.f));
        pk1[0][m] = q.u;
        q.p = __builtin_amdgcn_cvt_pkrtz(fmaxf(acc11[2*m], 0.f), fmaxf(acc11[2*m+1], 0.f));
        pk1[1][m] = q.u;
    }
    if (hl == 0) { pk1[0][5] = 0x3C00u; pk1[1][5] = 0x3C00u; }  // F-row 50 = 1

    f32x16 acch0, acch1;
    #pragma unroll
    for (int r = 0; r < 16; ++r) { acch0[r] = 0.f; acch1[r] = 0.f; }

    #pragma unroll
    for (int kt = 0; kt < 4; ++kt) {
        half8 ah = *(const half8*)(whp + kt * 512 + lane * 8);
        const int bb = 4 * (kt & 1);
        #pragma unroll
        for (int ct = 0; ct < 2; ++ct) {
            const uint32_t e0 = (kt < 2) ? pk0[ct][bb + 0] : pk1[ct][bb + 0];
            const uint32_t e1 = (kt < 2) ? pk0[ct][bb + 1] : pk1[ct][bb + 1];
            const uint32_t e2 = (kt < 2) ? pk0[ct][bb + 2] : pk1[ct][bb + 2];
            const uint32_t e3 = (kt < 2) ? pk0[ct][bb + 3] : pk1[ct][bb + 3];
            const uint32_t o0 = hl ? e2 : e0;
            const uint32_t o1 = hl ? e3 : e1;
            const uint32_t s0 = hl ? e0 : e2;
            const uint32_t s1 = hl ? e1 : e3;
            const uint32_t g0 = (uint32_t)__shfl_xor((int)s0, 32);
            const uint32_t g1 = (uint32_t)__shfl_xor((int)s1, 32);
            union { half8 h; uint32_t u[4]; } BF;
            BF.u[0] = hl ? g0 : o0;
            BF.u[1] = hl ? g1 : o1;
            BF.u[2] = hl ? o0 : g0;
            BF.u[3] = hl ? o1 : g1;
            if (ct == 0) acch0 = __builtin_amdgcn_mfma_f32_32x32x16_f16(ah, BF.h, acch0, 0, 0, 0);
            else         acch1 = __builtin_amdgcn_mfma_f32_32x32x16_f16(ah, BF.h, acch1, 0, 0, 0);
        }
    }

    float s[9];
    #pragma unroll
    for (int r = 0; r < 4; ++r) {
        const float own  = hl ? acch1[r] : acch0[r];
        const float send = hl ? acch0[r] : acch1[r];
        const float got  = __shfl_xor(send, 32);
        s[r]     = hl ? got : own;
        s[4 + r] = hl ? own : got;
    }
    {
        const float own  = hl ? acch1[4] : acch0[4];
        const float send = hl ? acch0[4] : acch1[4];
        const float got  = __shfl_xor(send, 32);
        s[8] = hl ? got : own;
    }

    const int p   = p0 + lane;
    const int b   = p >> 16;
    const int pix = p & 65535;
    const int ph  = pix >> 8;
    const int pw  = pix & 255;

    float pan = s[4];
    #pragma unroll
    for (int c = 0; c < 4; ++c)
        pan = fmaf(hrhs[((b * 4 + c) << 16) + pix], s[c], pan);
    out_pan[p] = pan;

    if ((ph & 3) == 1 && (pw & 3) == 1) {
        const float v0 = s[5], v2 = s[7], v3 = s[8];
        const int hh = ph >> 2, ww = pw >> 2;
        const int o = ((b * LSZ + hh) * LSZ + ww) * 3;
        inv_ws[o + 0] = v0 * v0 + v2 * v2;
        inv_ws[o + 1] = v2 * v3;
        inv_ws[o + 2] = v3 * v3;
    }
}

// ---------------------------------------------------------------------------
// msi2 (unchanged, verified): shared Gaussian weights in LDS + float4
// gathers from padded planes.
// ---------------------------------------------------------------------------
__global__ __launch_bounds__(256) void msi2_kernel(
    const float* __restrict__ pad, const float* __restrict__ inv_ws,
    float* __restrict__ out_msi)
{
    __shared__ float ew[225 * 64];   // 57600 B, [p*15+q][ww]
    __shared__ float wsp[256];

    const int tid = threadIdx.x;
    const int ww  = tid & 63;
    const int c   = tid >> 6;
    const int hh  = blockIdx.x & 63;
    const int b   = blockIdx.x >> 6;

    const int o = ((b * LSZ + hh) * LSZ + ww) * 3;
    const float I00 = inv_ws[o + 0];
    const float I01 = inv_ws[o + 1];
    const float I11 = inv_ws[o + 2];

    float ws = 0.0f;
    #pragma unroll
    for (int pp = 0; pp < 4; ++pp) {
        const int p = c * 4 + pp;
        if (p > 14) break;
        const float dp = (float)(p - 7);
        const float a0 = I00 * dp * dp;
        const float a1 = 2.0f * I01 * dp;
        #pragma unroll
        for (int q = 0; q < 15; ++q) {
            const float dq = (float)(q - 7);
            const float tt = fmaf(a1, dq, fmaf(I11 * dq, dq, a0));
            const float e = __expf(-0.5f * tt);
            ew[(p * 15 + q) * 64 + ww] = e;
            ws += e;
        }
    }
    wsp[tid] = ws;
    __syncthreads();

    const float wsum = wsp[ww] + wsp[64 + ww] + wsp[128 + ww] + wsp[192 + ww];
    const float* plane = pad + (size_t)((b * 4 + c) * PROWS) * PCOLS;

    float acc = 0.0f;
    #pragma unroll
    for (int p = 0; p < 15; ++p) {
        const float* rowp = plane + (4 * hh + p) * PCOLS + 4 * ww;
        const float4 x0 = *(const float4*)(rowp);
        const float4 x1 = *(const float4*)(rowp + 4);
        const float4 x2 = *(const float4*)(rowp + 8);
        const float4 x3 = *(const float4*)(rowp + 12);
        const float xs[16] = {x0.x,x0.y,x0.z,x0.w, x1.x,x1.y,x1.z,x1.w,
                              x2.x,x2.y,x2.z,x2.w, x3.x,x3.y,x3.z,x3.w};
        #pragma unroll
        for (int q = 0; q < 15; ++q)
            acc = fmaf(xs[q], ew[(p * 15 + q) * 64 + ww], acc);
    }
    out_msi[((b * 4 + c) * LSZ + hh) * LSZ + ww] = acc / wsum;
}

extern "C" void kernel_launch(void* const* d_in, const int* in_sizes, int n_in,
                              void* d_out, int out_size, void* d_ws, size_t ws_size,
                              hipStream_t stream) {
    const float* coords = (const float*)d_in[0];
    const float* hrhs   = (const float*)d_in[1];
    const float* w1     = (const float*)d_in[2];
    const float* b1     = (const float*)d_in[3];
    const float* w2     = (const float*)d_in[4];
    const float* b2     = (const float*)d_in[5];
    const float* w_spek = (const float*)d_in[6];
    const float* b_spek = (const float*)d_in[7];
    const float* w_spak = (const float*)d_in[8];
    const float* b_spak = (const float*)d_in[9];

    float* out     = (float*)d_out;
    float* out_msi = out;                        // 8*4*64*64   = 131072
    float* out_pan = out + 8 * 4 * 64 * 64;      // 8*1*256*256 = 524288

    float*     inv_ws = (float*)d_ws;                         // 393216 B
    _Float16*  w2p    = (_Float16*)((char*)d_ws + 393216);    // 28672 B
    _Float16*  whp    = (_Float16*)((char*)d_ws + 421888);    // 4096 B
    _Float16*  w1p    = (_Float16*)((char*)d_ws + 425984);    // 4096 B (1248 used)
    float*     padbuf = (float*)((char*)d_ws + 430080);       // 9295872 B

    const int n_prep = PACK_THREADS / 256 + PAD_N / 256;      // 67 + 9078
    prep_kernel<<<n_prep, 256, 0, stream>>>(
        w1, b1, w2, b2, w_spek, b_spek, w_spak, b_spak, hrhs,
        w2p, whp, w1p, padbuf);

    mlp11_kernel<<<1024, 512, 0, stream>>>(
        coords, hrhs, w1p, w2p, whp, out_pan, inv_ws);

    msi2_kernel<<<512, 256, 0, stream>>>(padbuf, inv_ws, out_msi);
}

// Round 15
// 38.895 us; speedup vs baseline: 1.0592x; 1.0096x over previous
//
#include <hip/hip_runtime.h>

#define HRR 256
#define LSZ 64
#define KK  15
#define PROWS 267
#define PCOLS 272

typedef _Float16 half8  __attribute__((ext_vector_type(8)));
typedef __fp16   fp16x2 __attribute__((ext_vector_type(2)));
typedef __fp16   h2     __attribute__((ext_vector_type(2)));
typedef float    f32x16 __attribute__((ext_vector_type(16)));

#define PACK_THREADS 17152   // 67 blocks
#define PAD_N (32 * PROWS * PCOLS)

// ---------------------------------------------------------------------------
// Prep kernel: weight packing (blocks 0..66) + hrhs zero-padding (rest).
// Unchanged (verified rounds 6-14).
// ---------------------------------------------------------------------------
__global__ __launch_bounds__(256) void prep_kernel(
    const float* __restrict__ w1,     const float* __restrict__ b1,
    const float* __restrict__ w2,     const float* __restrict__ b2,
    const float* __restrict__ w_spek, const float* __restrict__ b_spek,
    const float* __restrict__ w_spak, const float* __restrict__ b_spak,
    const float* __restrict__ hrhs,
    _Float16* __restrict__ w2p, _Float16* __restrict__ whp,
    _Float16* __restrict__ w1p, float* __restrict__ pad)
{
    int gid = blockIdx.x * 256 + threadIdx.x;
    if (gid < PACK_THREADS) {
        int flat = gid;
        if (flat < 14336) {
            int rt = flat / 7168;
            int rem = flat % 7168;
            int f  = rem / 512;
            int r2 = rem % 512;
            int ln = r2 / 8;
            int i  = r2 % 8;
            int j = rt * 32 + (ln & 31);
            int k = f * 16 + (ln >> 5) * 8 + i;
            float v = 0.0f;
            if (j < 50) {
                if (k < 200)       v = w2[k * 50 + j];
                else if (k == 200) v = b2[j];
            }
            w2p[flat] = (_Float16)v;
        } else if (flat < 14336 + 2048) {
            int r  = flat - 14336;
            int f  = r / 512;
            int r2 = r % 512;
            int ln = r2 / 8;
            int i  = r2 % 8;
            int t = ln & 31;
            int k = f * 16 + (ln >> 5) * 8 + i;
            float v = 0.0f;
            if (t < 9) {
                if (k < 50)       v = (t < 5) ? w_spek[k * 5 + t] : w_spak[k * 4 + (t - 5)];
                else if (k == 50) v = (t < 5) ? b_spek[t] : b_spak[t - 5];
            }
            whp[r] = (_Float16)v;
        } else if (flat < 14336 + 2048 + 624) {
            int r = flat - (14336 + 2048);
            int e  = r & 1;
            int pr = (r >> 1) % 12;
            int hl = ((r >> 1) / 12) & 1;
            int f  = (r >> 1) / 24;
            int k  = f * 16 + hl * 8 + (pr & 3) * 2 + e;
            int sel = pr >> 2;                  // 0 wa, 1 wb, 2 bv
            float v = 0.0f;
            if (k < 200)       v = (sel == 0) ? w1[k] : (sel == 1) ? w1[200 + k] : b1[k];
            else if (k == 200 && sel == 2) v = 1.0f;   // bias ones-row
            w1p[r] = (_Float16)v;
        }
    } else {
        int i = gid - PACK_THREADS;
        if (i < PAD_N) {
            int pc   = i % PCOLS;
            int rest = i / PCOLS;
            int pr   = rest % PROWS;
            int bc   = rest / PROWS;
            int r    = pr - 6;
            int col  = pc - 6;
            float v = ((unsigned)r < 256u && (unsigned)col < 256u)
                          ? hrhs[(bc << 16) + (r << 8) + col] : 0.0f;
            pad[i] = v;
        }
    }
}

// ---------------------------------------------------------------------------
// Main MLP kernel, round-15: round-12 winner (512-thread blocks, 64 pts/wave,
// LDS-staged weights) + s_setprio(1)/(0) around both MFMA clusters.
// Mechanism: independent 4-block-per-CU residency puts waves in different
// phases (staging / layer-1 VALU / MFMA / head / epilogue); setprio biases
// the CU scheduler toward MFMA-issuing waves (measured +4-7% in the
// phase-diverse regime, null only under barrier-lockstep).
// ---------------------------------------------------------------------------
__global__ __launch_bounds__(512, 4) void mlp12_kernel(
    const float* __restrict__ coords, const float* __restrict__ hrhs,
    const _Float16* __restrict__ w1p,
    const _Float16* __restrict__ w2p, const _Float16* __restrict__ whp,
    float* __restrict__ out_pan,      float* __restrict__ inv_ws)
{
    __shared__ __align__(16) _Float16 W2s[14336];   // 28672 B
    __shared__ __align__(16) _Float16 W1s[624];     // 1248 B

    const int tid  = threadIdx.x;
    const int lane = tid & 63;
    const int wv   = tid >> 6;      // 0..7
    const int hl   = lane >> 5;
    const int cl   = lane & 31;

    {
        const uint4* src = (const uint4*)w2p;
        uint4* dst = (uint4*)W2s;
        #pragma unroll
        for (int it = 0; it < 3; ++it)
            dst[it * 512 + tid] = src[it * 512 + tid];
        if (tid < 256) dst[1536 + tid] = src[1536 + tid];
        if (tid < 312) ((unsigned*)W1s)[tid] = ((const unsigned*)w1p)[tid];
    }
    __syncthreads();

    const int p0 = blockIdx.x * 512 + wv * 64;

    const float2 cA = ((const float2*)coords)[p0 + cl];        // ct = 0
    const float2 cB = ((const float2*)coords)[p0 + 32 + cl];   // ct = 1

    const __fp16 ax = (__fp16)cA.x, ay = (__fp16)cA.y;
    const __fp16 bx = (__fp16)cB.x, by = (__fp16)cB.y;
    const h2 cax2 = {ax, ax}, cay2 = {ay, ay};
    const h2 cbx2 = {bx, bx}, cby2 = {by, by};
    const h2 hz   = {(__fp16)0.f, (__fp16)0.f};

    f32x16 acc00, acc01, acc10, acc11;
    #pragma unroll
    for (int r = 0; r < 16; ++r) { acc00[r] = 0.f; acc01[r] = 0.f; acc10[r] = 0.f; acc11[r] = 0.f; }

    const _Float16* w1base = W1s + hl * 24;

    for (int f = 0; f < 13; ++f) {
        half8 a0 = *(const half8*)(W2s + f * 512 + lane * 8);
        half8 a1 = *(const half8*)(W2s + (14 + f) * 512 + lane * 8);

        union { uint4 u[3]; h2 p[12]; } W;
        const uint4* wp = (const uint4*)(w1base + f * 48);
        W.u[0] = wp[0]; W.u[1] = wp[1]; W.u[2] = wp[2];

        union { half8 h; h2 p[4]; } B0, B1;
        #pragma unroll
        for (int m = 0; m < 4; ++m) {
            h2 t0 = __builtin_elementwise_fma(W.p[4 + m], cay2, W.p[8 + m]);
            h2 r0 = __builtin_elementwise_fma(W.p[m],     cax2, t0);
            B0.p[m] = __builtin_elementwise_max(r0, hz);
            h2 t1 = __builtin_elementwise_fma(W.p[4 + m], cby2, W.p[8 + m]);
            h2 r1 = __builtin_elementwise_fma(W.p[m],     cbx2, t1);
            B1.p[m] = __builtin_elementwise_max(r1, hz);
        }

        __builtin_amdgcn_s_setprio(1);
        acc00 = __builtin_amdgcn_mfma_f32_32x32x16_f16(a0, B0.h, acc00, 0, 0, 0);
        acc01 = __builtin_amdgcn_mfma_f32_32x32x16_f16(a0, B1.h, acc01, 0, 0, 0);
        acc10 = __builtin_amdgcn_mfma_f32_32x32x16_f16(a1, B0.h, acc10, 0, 0, 0);
        acc11 = __builtin_amdgcn_mfma_f32_32x32x16_f16(a1, B1.h, acc11, 0, 0, 0);
        __builtin_amdgcn_s_setprio(0);
    }

    uint32_t pk0[2][8], pk1[2][8];
    #pragma unroll
    for (int m = 0; m < 8; ++m) {
        union { fp16x2 p; uint32_t u; } q;
        q.p = __builtin_amdgcn_cvt_pkrtz(fmaxf(acc00[2*m], 0.f), fmaxf(acc00[2*m+1], 0.f));
        pk0[0][m] = q.u;
        q.p = __builtin_amdgcn_cvt_pkrtz(fmaxf(acc01[2*m], 0.f), fmaxf(acc01[2*m+1], 0.f));
        pk0[1][m] = q.u;
        q.p = __builtin_amdgcn_cvt_pkrtz(fmaxf(acc10[2*m], 0.f), fmaxf(acc10[2*m+1], 0.f));
        pk1[0][m] = q.u;
        q.p = __builtin_amdgcn_cvt_pkrtz(fmaxf(acc11[2*m], 0.f), fmaxf(acc11[2*m+1], 0.f));
        pk1[1][m] = q.u;
    }
    if (hl == 0) { pk1[0][5] = 0x3C00u; pk1[1][5] = 0x3C00u; }  // F-row 50 = 1

    f32x16 acch0, acch1;
    #pragma unroll
    for (int r = 0; r < 16; ++r) { acch0[r] = 0.f; acch1[r] = 0.f; }

    #pragma unroll
    for (int kt = 0; kt < 4; ++kt) {
        half8 ah = *(const half8*)(whp + kt * 512 + lane * 8);
        const int bb = 4 * (kt & 1);
        #pragma unroll
        for (int ct = 0; ct < 2; ++ct) {
            const uint32_t e0 = (kt < 2) ? pk0[ct][bb + 0] : pk1[ct][bb + 0];
            const uint32_t e1 = (kt < 2) ? pk0[ct][bb + 1] : pk1[ct][bb + 1];
            const uint32_t e2 = (kt < 2) ? pk0[ct][bb + 2] : pk1[ct][bb + 2];
            const uint32_t e3 = (kt < 2) ? pk0[ct][bb + 3] : pk1[ct][bb + 3];
            const uint32_t o0 = hl ? e2 : e0;
            const uint32_t o1 = hl ? e3 : e1;
            const uint32_t s0 = hl ? e0 : e2;
            const uint32_t s1 = hl ? e1 : e3;
            const uint32_t g0 = (uint32_t)__shfl_xor((int)s0, 32);
            const uint32_t g1 = (uint32_t)__shfl_xor((int)s1, 32);
            union { half8 h; uint32_t u[4]; } BF;
            BF.u[0] = hl ? g0 : o0;
            BF.u[1] = hl ? g1 : o1;
            BF.u[2] = hl ? o0 : g0;
            BF.u[3] = hl ? o1 : g1;
            __builtin_amdgcn_s_setprio(1);
            if (ct == 0) acch0 = __builtin_amdgcn_mfma_f32_32x32x16_f16(ah, BF.h, acch0, 0, 0, 0);
            else         acch1 = __builtin_amdgcn_mfma_f32_32x32x16_f16(ah, BF.h, acch1, 0, 0, 0);
            __builtin_amdgcn_s_setprio(0);
        }
    }

    float s[9];
    #pragma unroll
    for (int r = 0; r < 4; ++r) {
        const float own  = hl ? acch1[r] : acch0[r];
        const float send = hl ? acch0[r] : acch1[r];
        const float got  = __shfl_xor(send, 32);
        s[r]     = hl ? got : own;
        s[4 + r] = hl ? own : got;
    }
    {
        const float own  = hl ? acch1[4] : acch0[4];
        const float send = hl ? acch0[4] : acch1[4];
        const float got  = __shfl_xor(send, 32);
        s[8] = hl ? got : own;
    }

    const int p   = p0 + lane;
    const int b   = p >> 16;
    const int pix = p & 65535;
    const int ph  = pix >> 8;
    const int pw  = pix & 255;

    float pan = s[4];
    #pragma unroll
    for (int c = 0; c < 4; ++c)
        pan = fmaf(hrhs[((b * 4 + c) << 16) + pix], s[c], pan);
    out_pan[p] = pan;

    if ((ph & 3) == 1 && (pw & 3) == 1) {
        const float v0 = s[5], v2 = s[7], v3 = s[8];
        const int hh = ph >> 2, ww = pw >> 2;
        const int o = ((b * LSZ + hh) * LSZ + ww) * 3;
        inv_ws[o + 0] = v0 * v0 + v2 * v2;
        inv_ws[o + 1] = v2 * v3;
        inv_ws[o + 2] = v3 * v3;
    }
}

// ---------------------------------------------------------------------------
// msi2 (unchanged, verified): shared Gaussian weights in LDS + float4
// gathers from padded planes.
// ---------------------------------------------------------------------------
__global__ __launch_bounds__(256) void msi2_kernel(
    const float* __restrict__ pad, const float* __restrict__ inv_ws,
    float* __restrict__ out_msi)
{
    __shared__ float ew[225 * 64];   // 57600 B, [p*15+q][ww]
    __shared__ float wsp[256];

    const int tid = threadIdx.x;
    const int ww  = tid & 63;
    const int c   = tid >> 6;
    const int hh  = blockIdx.x & 63;
    const int b   = blockIdx.x >> 6;

    const int o = ((b * LSZ + hh) * LSZ + ww) * 3;
    const float I00 = inv_ws[o + 0];
    const float I01 = inv_ws[o + 1];
    const float I11 = inv_ws[o + 2];

    float ws = 0.0f;
    #pragma unroll
    for (int pp = 0; pp < 4; ++pp) {
        const int p = c * 4 + pp;
        if (p > 14) break;
        const float dp = (float)(p - 7);
        const float a0 = I00 * dp * dp;
        const float a1 = 2.0f * I01 * dp;
        #pragma unroll
        for (int q = 0; q < 15; ++q) {
            const float dq = (float)(q - 7);
            const float tt = fmaf(a1, dq, fmaf(I11 * dq, dq, a0));
            const float e = __expf(-0.5f * tt);
            ew[(p * 15 + q) * 64 + ww] = e;
            ws += e;
        }
    }
    wsp[tid] = ws;
    __syncthreads();

    const float wsum = wsp[ww] + wsp[64 + ww] + wsp[128 + ww] + wsp[192 + ww];
    const float* plane = pad + (size_t)((b * 4 + c) * PROWS) * PCOLS;

    float acc = 0.0f;
    #pragma unroll
    for (int p = 0; p < 15; ++p) {
        const float* rowp = plane + (4 * hh + p) * PCOLS + 4 * ww;
        const float4 x0 = *(const float4*)(rowp);
        const float4 x1 = *(const float4*)(rowp + 4);
        const float4 x2 = *(const float4*)(rowp + 8);
        const float4 x3 = *(const float4*)(rowp + 12);
        const float xs[16] = {x0.x,x0.y,x0.z,x0.w, x1.x,x1.y,x1.z,x1.w,
                              x2.x,x2.y,x2.z,x2.w, x3.x,x3.y,x3.z,x3.w};
        #pragma unroll
        for (int q = 0; q < 15; ++q)
            acc = fmaf(xs[q], ew[(p * 15 + q) * 64 + ww], acc);
    }
    out_msi[((b * 4 + c) * LSZ + hh) * LSZ + ww] = acc / wsum;
}

extern "C" void kernel_launch(void* const* d_in, const int* in_sizes, int n_in,
                              void* d_out, int out_size, void* d_ws, size_t ws_size,
                              hipStream_t stream) {
    const float* coords = (const float*)d_in[0];
    const float* hrhs   = (const float*)d_in[1];
    const float* w1     = (const float*)d_in[2];
    const float* b1     = (const float*)d_in[3];
    const float* w2     = (const float*)d_in[4];
    const float* b2     = (const float*)d_in[5];
    const float* w_spek = (const float*)d_in[6];
    const float* b_spek = (const float*)d_in[7];
    const float* w_spak = (const float*)d_in[8];
    const float* b_spak = (const float*)d_in[9];

    float* out     = (float*)d_out;
    float* out_msi = out;                        // 8*4*64*64   = 131072
    float* out_pan = out + 8 * 4 * 64 * 64;      // 8*1*256*256 = 524288

    float*     inv_ws = (float*)d_ws;                         // 393216 B
    _Float16*  w2p    = (_Float16*)((char*)d_ws + 393216);    // 28672 B
    _Float16*  whp    = (_Float16*)((char*)d_ws + 421888);    // 4096 B
    _Float16*  w1p    = (_Float16*)((char*)d_ws + 425984);    // 4096 B (1248 used)
    float*     padbuf = (float*)((char*)d_ws + 430080);       // 9295872 B

    const int n_prep = PACK_THREADS / 256 + PAD_N / 256;      // 67 + 9078
    prep_kernel<<<n_prep, 256, 0, stream>>>(
        w1, b1, w2, b2, w_spek, b_spek, w_spak, b_spak, hrhs,
        w2p, whp, w1p, padbuf);

    mlp12_kernel<<<1024, 512, 0, stream>>>(
        coords, hrhs, w1p, w2p, whp, out_pan, inv_ws);

    msi2_kernel<<<512, 256, 0, stream>>>(padbuf, inv_ws, out_msi);
}